// Round 2
// baseline (5124.865 us; speedup 1.0000x reference)
//
#include <hip/hip_runtime.h>

#define B_ 8
#define C_ 64
#define H_ 256
#define W_ 256
#define HW_ 65536
#define SLOPE_ 0.01f
#define EPS_ 1e-5f
#define CROP_ 244
#define NPIX_ 59536.0f

typedef unsigned short ushortT;

__device__ __forceinline__ float lrelu(float v) { return v >= 0.f ? v : SLOPE_ * v; }
__device__ __forceinline__ int clampi(int v, int lo, int hi) { return v < lo ? lo : (v > hi ? hi : v); }

__device__ __forceinline__ ushortT f2bf(float f) {
    union { float f; unsigned u; } v; v.f = f;
    unsigned r = v.u + 0x7FFF + ((v.u >> 16) & 1);
    return (ushortT)(r >> 16);
}
__device__ __forceinline__ float bf2f(ushortT h) {
    union { unsigned u; float f; } v; v.u = ((unsigned)h) << 16;
    return v.f;
}

// ---------------- weight transpose: ws (7,oc64,ic64,3,3) -> wT [l][ic][tap][oc]
__global__ void wtrans_kernel(const float* __restrict__ ws, float* __restrict__ wT) {
    int idx = blockIdx.x * 256 + threadIdx.x;           // 0..258047
    if (idx >= 7 * 64 * 64 * 9) return;
    int l = idx / 36864;
    int r = idx - l * 36864;                            // ((ic*9+tap))*64 + oc
    int oc = r & 63;
    int t = r >> 6;
    int ic = t / 9;
    int tap = t - ic * 9;
    wT[idx] = ws[l * 36864 + (oc * 64 + ic) * 9 + tap];
}

// ---------------- conv0: 1->64, block per (b,oc) plane; writes raw y0 (bf16) + norm params
__global__ __launch_bounds__(256) void conv0_kernel(
    const float* __restrict__ xin, const float* __restrict__ w0,
    const float* __restrict__ b0, ushortT* __restrict__ yout,
    float* __restrict__ normp) {
    int b = blockIdx.x >> 6;
    int oc = blockIdx.x & 63;
    float w[9];
#pragma unroll
    for (int i = 0; i < 9; i++) w[i] = w0[oc * 9 + i];
    float bias = b0[oc];
    const float* xp = xin + b * HW_;
    ushortT* yp = yout + (b * C_ + oc) * HW_;
    float s = 0.f, s2 = 0.f;
    for (int px = threadIdx.x; px < HW_; px += 256) {
        int y = px >> 8, x = px & 255;
        float acc = bias;
#pragma unroll
        for (int ky = 0; ky < 3; ky++) {
            int iy = clampi(y + ky - 1, 0, 255);
#pragma unroll
            for (int kx = 0; kx < 3; kx++) {
                int ix = clampi(x + kx - 1, 0, 255);
                acc = fmaf(w[ky * 3 + kx], xp[(iy << 8) + ix], acc);
            }
        }
        yp[px] = f2bf(acc);
        s += acc; s2 += acc * acc;
    }
    __shared__ float rs[4], rs2[4];
#pragma unroll
    for (int m = 1; m < 64; m <<= 1) { s += __shfl_xor(s, m); s2 += __shfl_xor(s2, m); }
    int lane = threadIdx.x & 63, wv = threadIdx.x >> 6;
    if (lane == 0) { rs[wv] = s; rs2[wv] = s2; }
    __syncthreads();
    if (threadIdx.x == 0) {
        float S = rs[0] + rs[1] + rs[2] + rs[3];
        float S2 = rs2[0] + rs2[1] + rs2[2] + rs2[3];
        float mean = S * (1.0f / HW_);
        float var = S2 * (1.0f / HW_) - mean * mean;
        float inv = rsqrtf(var + EPS_);
        normp[(b * C_ + oc) * 2] = inv;
        normp[(b * C_ + oc) * 2 + 1] = -mean * inv;
    }
}

// ---------------- mid conv: 64->64, fused input norm+lrelu, LDS tiled
// tile: 8 rows x 32 cols output, all 64 oc. 256 threads: og=tid&7 (8 oc), pg=tid>>3 (8 px)
#define TOH 8
#define TOW 32
#define ICC 32
__global__ __launch_bounds__(256, 3) void conv_mid_kernel(
    const ushortT* __restrict__ yin, const float* __restrict__ normp,
    const float* __restrict__ wT, const float* __restrict__ bias,
    ushortT* __restrict__ yout, float* __restrict__ partial) {
    __shared__ float s_in[ICC * 10 * 36];   // 45 KiB
    __shared__ float wred[4][64][2];        // 2 KiB
    int tile = blockIdx.x;                  // 0..255
    int b = blockIdx.y;                     // 0..7
    int ty = tile >> 3;
    int tx = tile & 7;
    int oy0 = ty * TOH, ox0 = tx * TOW;
    int tid = threadIdx.x;
    int og = tid & 7;
    int pg = tid >> 3;
    int prow = pg >> 2;
    int pxb = (pg & 3) << 3;

    float acc[8][8];
#pragma unroll
    for (int j = 0; j < 8; j++)
#pragma unroll
        for (int k = 0; k < 8; k++) acc[j][k] = 0.f;

    for (int c0 = 0; c0 < C_; c0 += ICC) {
        // stage input chunk with norm + lrelu fused, replicate pad
        for (int idx = tid; idx < ICC * 10 * 34; idx += 256) {
            int ic = idx / 340;
            int rem = idx - ic * 340;
            int r = rem / 34;
            int c = rem - r * 34;
            int iy = clampi(oy0 - 1 + r, 0, 255);
            int ix = clampi(ox0 - 1 + c, 0, 255);
            int ch = c0 + ic;
            float a = normp[(b * C_ + ch) * 2];
            float bb = normp[(b * C_ + ch) * 2 + 1];
            float v = bf2f(yin[((b * C_ + ch) << 16) + (iy << 8) + ix]);
            v = lrelu(fmaf(v, a, bb));
            s_in[(ic * 10 + r) * 36 + c] = v;
        }
        __syncthreads();
        for (int ic = 0; ic < ICC; ic++) {
            const float* wbase = wT + ((c0 + ic) * 9) * 64 + og * 8;
#pragma unroll
            for (int ky = 0; ky < 3; ky++) {
                const float* rp = &s_in[(ic * 10 + prow + ky) * 36 + pxb];
                float4 r0 = *(const float4*)rp;
                float4 r1 = *(const float4*)(rp + 4);
                float4 r2 = *(const float4*)(rp + 8);
                float rowv[12] = {r0.x, r0.y, r0.z, r0.w, r1.x, r1.y, r1.z, r1.w,
                                  r2.x, r2.y, r2.z, r2.w};
#pragma unroll
                for (int kx = 0; kx < 3; kx++) {
                    const float* wp0 = wbase + (ky * 3 + kx) * 64;
                    float4 wa = *(const float4*)wp0;
                    float4 wb = *(const float4*)(wp0 + 4);
                    float wv[8] = {wa.x, wa.y, wa.z, wa.w, wb.x, wb.y, wb.z, wb.w};
#pragma unroll
                    for (int j = 0; j < 8; j++)
#pragma unroll
                        for (int k = 0; k < 8; k++)
                            acc[j][k] = fmaf(rowv[kx + j], wv[k], acc[j][k]);
                }
            }
        }
        __syncthreads();
    }

    // bias, write (bf16), per-thread stats
    float ssum[8], ssq[8];
#pragma unroll
    for (int k = 0; k < 8; k++) {
        int oc = og * 8 + k;
        float bv = bias[oc];
        ushortT* op = yout + ((b * C_ + oc) << 16) + ((oy0 + prow) << 8) + ox0 + pxb;
        float v0 = acc[0][k] + bv, v1 = acc[1][k] + bv, v2 = acc[2][k] + bv, v3 = acc[3][k] + bv;
        float v4 = acc[4][k] + bv, v5 = acc[5][k] + bv, v6 = acc[6][k] + bv, v7 = acc[7][k] + bv;
        uint4 pk;
        pk.x = (unsigned)f2bf(v0) | ((unsigned)f2bf(v1) << 16);
        pk.y = (unsigned)f2bf(v2) | ((unsigned)f2bf(v3) << 16);
        pk.z = (unsigned)f2bf(v4) | ((unsigned)f2bf(v5) << 16);
        pk.w = (unsigned)f2bf(v6) | ((unsigned)f2bf(v7) << 16);
        *(uint4*)op = pk;
        ssum[k] = v0 + v1 + v2 + v3 + v4 + v5 + v6 + v7;
        ssq[k] = v0 * v0 + v1 * v1 + v2 * v2 + v3 * v3 + v4 * v4 + v5 * v5 + v6 * v6 + v7 * v7;
    }
    // reduce across the 8 pixel-groups in this wave (lanes differing in bits 3..5)
#pragma unroll
    for (int m = 8; m <= 32; m <<= 1)
#pragma unroll
        for (int k = 0; k < 8; k++) {
            ssum[k] += __shfl_xor(ssum[k], m);
            ssq[k] += __shfl_xor(ssq[k], m);
        }
    int lane = tid & 63, wv = tid >> 6;
    if (lane < 8) {
#pragma unroll
        for (int k = 0; k < 8; k++) {
            wred[wv][lane * 8 + k][0] = ssum[k];
            wred[wv][lane * 8 + k][1] = ssq[k];
        }
    }
    __syncthreads();
    if (tid < 128) {
        int k2 = tid & 1, oc = tid >> 1;
        float v = wred[0][oc][k2] + wred[1][oc][k2] + wred[2][oc][k2] + wred[3][oc][k2];
        partial[(((b << 8) + tile) << 7) + oc * 2 + k2] = v;
    }
}

// ---------------- reduce per-tile partials -> norm params
__global__ void statfin_kernel(const float* __restrict__ partial, float* __restrict__ normp) {
    int idx = blockIdx.x * 256 + threadIdx.x;  // 0..511
    if (idx >= B_ * C_) return;
    int b = idx >> 6, oc = idx & 63;
    float s = 0.f, s2 = 0.f;
    for (int t = 0; t < 256; t++) {
        const float* p = partial + ((b << 8) + t) * 128 + oc * 2;
        s += p[0];
        s2 += p[1];
    }
    float mean = s * (1.0f / HW_);
    float var = s2 * (1.0f / HW_) - mean * mean;
    float inv = rsqrtf(var + EPS_);
    normp[idx * 2] = inv;
    normp[idx * 2 + 1] = -mean * inv;
}

// ---------------- projection 64->1 + residual -> hr (d_out)
__global__ __launch_bounds__(256) void proj_kernel(
    const ushortT* __restrict__ y7, const float* __restrict__ normp,
    const float* __restrict__ wp, const float* __restrict__ bp,
    const float* __restrict__ xin, float* __restrict__ out) {
    int idx = blockIdx.x * 256 + threadIdx.x;
    if (idx >= B_ * HW_) return;
    int b = idx >> 16;
    int px = idx & 65535;
    int y = px >> 8, x = px & 255;
    int iy[3], ix[3];
#pragma unroll
    for (int t = 0; t < 3; t++) {
        iy[t] = clampi(y + t - 1, 0, 255);
        ix[t] = clampi(x + t - 1, 0, 255);
    }
    float acc = bp[0];
    for (int ic = 0; ic < 64; ic++) {
        float a = normp[(b * C_ + ic) * 2];
        float bb = normp[(b * C_ + ic) * 2 + 1];
        const ushortT* ypb = y7 + ((b * C_ + ic) << 16);
#pragma unroll
        for (int ky = 0; ky < 3; ky++)
#pragma unroll
            for (int kx = 0; kx < 3; kx++) {
                float v = bf2f(ypb[(iy[ky] << 8) + ix[kx]]);
                acc = fmaf(lrelu(fmaf(v, a, bb)), wp[ic * 9 + ky * 3 + kx], acc);
            }
    }
    out[idx] = acc + xin[idx];
}

// ---------------- loss: per (offset,b) sum & sumsq of d = crop - t
__global__ __launch_bounds__(256) void loss_main_kernel(
    const float* __restrict__ hr, const float* __restrict__ target,
    float* __restrict__ lossS) {
    int off = blockIdx.x;  // 0..168
    int b = blockIdx.y;    // 0..7
    int oy = off / 13, ox = off - oy * 13;
    const float* hp = hr + b * HW_ + (oy << 8) + ox;
    const float* tp = target + b * HW_ + (6 << 8) + 6;
    float s = 0.f, s2 = 0.f;
    for (int i = threadIdx.x; i < CROP_ * CROP_; i += 256) {
        int y = i / CROP_;
        int x = i - y * CROP_;
        float d = hp[(y << 8) + x] - tp[(y << 8) + x];
        s += d; s2 += d * d;
    }
    __shared__ float rs[4], rs2[4];
#pragma unroll
    for (int m = 1; m < 64; m <<= 1) { s += __shfl_xor(s, m); s2 += __shfl_xor(s2, m); }
    int lane = threadIdx.x & 63, wv = threadIdx.x >> 6;
    if (lane == 0) { rs[wv] = s; rs2[wv] = s2; }
    __syncthreads();
    if (threadIdx.x == 0) {
        float S = rs[0] + rs[1] + rs[2] + rs[3];
        float S2 = rs2[0] + rs2[1] + rs2[2] + rs2[3];
        lossS[(off * 8 + b) * 2] = S;
        lossS[(off * 8 + b) * 2 + 1] = S2;
    }
}

__global__ void loss_final_kernel(const float* __restrict__ lossS, float* __restrict__ out) {
    int b = threadIdx.x;
    float mn = 0.f;
    if (b < 8) {
        mn = 1e30f;
        for (int off = 0; off < 169; off++) {
            float s = lossS[(off * 8 + b) * 2];
            float s2 = lossS[(off * 8 + b) * 2 + 1];
            float m = s * (1.0f / NPIX_);
            float L = s2 * (1.0f / NPIX_) - m * m;
            mn = fminf(mn, L);
        }
    }
#pragma unroll
    for (int m = 1; m < 8; m <<= 1) mn += __shfl_xor(mn, m);
    if (b == 0) out[0] = mn * 0.125f;
}

extern "C" void kernel_launch(void* const* d_in, const int* in_sizes, int n_in,
                              void* d_out, int out_size, void* d_ws, size_t ws_size,
                              hipStream_t stream) {
    const float* xIn    = (const float*)d_in[0];
    const float* target = (const float*)d_in[1];
    const float* w0     = (const float*)d_in[2];
    const float* b0     = (const float*)d_in[3];
    const float* wsAll  = (const float*)d_in[4];
    const float* bsAll  = (const float*)d_in[5];
    const float* wp     = (const float*)d_in[6];
    const float* bp     = (const float*)d_in[7];
    float* out = (float*)d_out;

    // small arrays first, big bf16 activation buffers after (~130 MB total)
    float* wT      = (float*)d_ws;                  // 258,048 f
    float* normp   = wT + 258048;                   // 1,024 f
    float* partial = normp + 1024;                  // 262,144 f
    float* lossS   = partial + 262144;              // 2,704 f
    ushortT* bufA  = (ushortT*)(lossS + 2704);      // 33,554,432 u16 (64 MiB)
    ushortT* bufB  = bufA + 33554432;               // 33,554,432 u16 (64 MiB)

    wtrans_kernel<<<1008, 256, 0, stream>>>(wsAll, wT);
    conv0_kernel<<<512, 256, 0, stream>>>(xIn, w0, b0, bufA, normp);
    for (int l = 0; l < 7; l++) {
        const ushortT* in = (l & 1) ? bufB : bufA;
        ushortT* o = (l & 1) ? bufA : bufB;
        conv_mid_kernel<<<dim3(256, 8), 256, 0, stream>>>(
            in, normp, wT + l * 36864, bsAll + l * 64, o, partial);
        statfin_kernel<<<2, 256, 0, stream>>>(partial, normp);
    }
    proj_kernel<<<(B_ * HW_ + 255) / 256, 256, 0, stream>>>(bufB, normp, wp, bp, xIn, out);
    loss_main_kernel<<<dim3(169, 8), 256, 0, stream>>>(out, target, lossS);
    loss_final_kernel<<<1, 64, 0, stream>>>(lossS, out + 524288);
}

// Round 5
// 935.940 us; speedup vs baseline: 5.4756x; 5.4756x over previous
//
#include <hip/hip_runtime.h>

#define B_ 8
#define C_ 64
#define HW_ 65536
#define SLOPE_ 0.01f
#define EPS_ 1e-5f
#define CROP_ 244
#define NPIX_ 59536.0f

typedef unsigned short u16;
typedef __attribute__((ext_vector_type(8))) _Float16 f16x8;
typedef __attribute__((ext_vector_type(4))) float f32x4;

__device__ __forceinline__ int clampi(int v, int lo, int hi) { return v < lo ? lo : (v > hi ? hi : v); }
__device__ __forceinline__ float lrelu(float v) { return fmaxf(v, 0.f) + SLOPE_ * fminf(v, 0.f); }

__device__ __forceinline__ u16 f2h(float f) {
    union { _Float16 h; u16 u; } v; v.h = (_Float16)f; return v.u;
}
__device__ __forceinline__ float h2f(u16 b) {
    union { u16 u; _Float16 h; } v; v.u = b; return (float)v.h;
}

// ---- weight pack: ws (7,oc64,ic64,3,3) fp32 -> wH f16 frag-major
// wH[l][tap][kb][mt][lane][j]: oc = mt*16 + (lane&15), ic = kb*32 + (lane>>4)*8 + j
__global__ void wtrans_kernel(const float* __restrict__ ws, u16* __restrict__ wH) {
    int idx = blockIdx.x * 256 + threadIdx.x;
    if (idx >= 7 * 36864) return;
    int l = idx / 36864;
    int rem = idx - l * 36864;
    int frag = rem >> 9;          // tap*8 + kb*4 + mt
    int lj = rem & 511;
    int lane = lj >> 3, j = lj & 7;
    int tap = frag >> 3, kb = (frag >> 2) & 1, mt = frag & 3;
    int oc = (mt << 4) + (lane & 15);
    int ic = (kb << 5) + ((lane >> 4) << 3) + j;
    wH[idx] = f2h(ws[((l * 64 + oc) * 64 + ic) * 9 + tap]);
}

// ---- conv0: 1->64, NHWC f16 output, per-thread pixel x all 64 oc
__global__ __launch_bounds__(256) void conv0_kernel(
    const float* __restrict__ xin, const float* __restrict__ w0,
    const float* __restrict__ b0, u16* __restrict__ yout) {
    __shared__ float w0s[576];
    __shared__ float b0s[64];
    int tid = threadIdx.x;
    for (int i = tid; i < 576; i += 256) w0s[i] = w0[i];
    if (tid < 64) b0s[tid] = b0[tid];
    __syncthreads();
    int pxg = blockIdx.x * 256 + tid;
    int b = pxg >> 16, px = pxg & 65535;
    int y = px >> 8, x = px & 255;
    float xv[9];
#pragma unroll
    for (int ky = 0; ky < 3; ky++)
#pragma unroll
        for (int kx = 0; kx < 3; kx++)
            xv[ky * 3 + kx] = xin[(b << 16) + (clampi(y + ky - 1, 0, 255) << 8) + clampi(x + kx - 1, 0, 255)];
    float acc[64];
#pragma unroll
    for (int k = 0; k < 64; k++) acc[k] = b0s[k];
#pragma unroll
    for (int t = 0; t < 9; t++) {
        float v = xv[t];
#pragma unroll
        for (int k = 0; k < 64; k++) acc[k] = fmaf(v, w0s[k * 9 + t], acc[k]);
    }
    uint4* op = (uint4*)(yout + ((size_t)pxg << 6));
#pragma unroll
    for (int c8 = 0; c8 < 8; c8++) {
        uint4 o;
        o.x = (unsigned)f2h(acc[c8 * 8 + 0]) | ((unsigned)f2h(acc[c8 * 8 + 1]) << 16);
        o.y = (unsigned)f2h(acc[c8 * 8 + 2]) | ((unsigned)f2h(acc[c8 * 8 + 3]) << 16);
        o.z = (unsigned)f2h(acc[c8 * 8 + 4]) | ((unsigned)f2h(acc[c8 * 8 + 5]) << 16);
        o.w = (unsigned)f2h(acc[c8 * 8 + 6]) | ((unsigned)f2h(acc[c8 * 8 + 7]) << 16);
        op[c8] = o;
    }
}

// ---- stats over NHWC f16 raw activations -> per-tile partial sums
__global__ __launch_bounds__(256) void stats0_kernel(const u16* __restrict__ yin, float* __restrict__ partial) {
    __shared__ float red[4][64][2];
    int tid = threadIdx.x;
    int tile = blockIdx.x, b = blockIdx.y;
    int oc = tid & 63, pq = tid >> 6;
    size_t base = (((size_t)(b << 16) + tile * 256 + (pq << 6)) << 6) + oc;
    float s = 0.f, s2 = 0.f;
    for (int i = 0; i < 64; i++) {
        float v = h2f(yin[base + ((size_t)i << 6)]);
        s += v; s2 += v * v;
    }
    red[pq][oc][0] = s; red[pq][oc][1] = s2;
    __syncthreads();
    if (tid < 128) {
        int o2 = tid >> 1, k2 = tid & 1;
        float v = red[0][o2][k2] + red[1][o2][k2] + red[2][o2][k2] + red[3][o2][k2];
        partial[(((b << 8) + tile) << 7) + (o2 << 1) + k2] = v;
    }
}

// ---- reduce per-tile partials -> norm params (inv, -mean*inv)
__global__ void statfin_kernel(const float* __restrict__ partial, float* __restrict__ normp) {
    int idx = blockIdx.x * 256 + threadIdx.x;
    if (idx >= B_ * C_) return;
    int b = idx >> 6, oc = idx & 63;
    float s = 0.f, s2 = 0.f;
    for (int t = 0; t < 256; t++) {
        const float* p = partial + ((b << 8) + t) * 128 + oc * 2;
        s += p[0]; s2 += p[1];
    }
    float mean = s * (1.0f / HW_);
    float var = s2 * (1.0f / HW_) - mean * mean;
    float inv = rsqrtf(var + EPS_);
    normp[idx * 2] = inv;
    normp[idx * 2 + 1] = -mean * inv;
}

// ---- mid conv 64->64 via MFMA implicit GEMM; NHWC f16 in/out
// block: 16x16 px tile, all 64 oc; 4 waves, wave w = rows 4w..4w+3
__global__ __launch_bounds__(256, 2) void conv_mid_kernel(
    const u16* __restrict__ yin, const float* __restrict__ normp,
    const u16* __restrict__ wH, const float* __restrict__ bias,
    u16* __restrict__ yout, float* __restrict__ partial) {
    __shared__ u16 s_in[324 * 64];      // 41472 B, ic-chunk XOR-swizzled by (px&7)
    __shared__ u16 s_w[2][4096];        // 16384 B, frag-major per tap (4096 u16 per tap)
    __shared__ float s_np[128];
    __shared__ float s_bias[64];
    __shared__ float s_red[4][64][2];

    int tid = threadIdx.x;
    int tile = blockIdx.x, b = blockIdx.y;
    int ty = tile >> 4, tx = tile & 15;
    int y0 = ty << 4, x0 = tx << 4;

    if (tid < 128) s_np[tid] = normp[(b << 7) + tid];
    if (tid < 64) s_bias[tid] = bias[tid];
    // stage tap0 weights: 4096 u16 = 256 threads x 16 u16 (2x uint4)
    {
        const uint4* src = (const uint4*)(wH + tid * 16);
        *(uint4*)(&s_w[0][tid * 16]) = src[0];
        *(uint4*)(&s_w[0][tid * 16 + 8]) = src[1];
    }
    __syncthreads();   // s_np ready for staging

    // stage 18x18 halo with norm + lrelu fused, replicate clamp, swizzled
    for (int chunk = tid; chunk < 2592; chunk += 256) {
        int px = chunk >> 3, c8 = chunk & 7;
        int row = px / 18;
        int col = px - row * 18;
        int iy = clampi(y0 - 1 + row, 0, 255);
        int ix = clampi(x0 - 1 + col, 0, 255);
        const uint4* gp = (const uint4*)(yin + ((((size_t)(b << 16)) + (iy << 8) + ix) << 6) + (c8 << 3));
        union { uint4 q; u16 h[8]; } ui, uo;
        ui.q = *gp;
#pragma unroll
        for (int i = 0; i < 8; i++) {
            int ch = (c8 << 3) + i;
            float v = h2f(ui.h[i]);
            v = fmaf(v, s_np[ch * 2], s_np[ch * 2 + 1]);
            v = lrelu(v);
            uo.h[i] = f2h(v);
        }
        int phys = c8 ^ (px & 7);
        *(uint4*)(&s_in[(px << 6) + (phys << 3)]) = uo.q;
    }
    __syncthreads();

    int lane = tid & 63, wv = tid >> 6;
    int m = lane & 15, q = lane >> 4;
    int r0 = wv << 2;

    f32x4 acc[4][4];
#pragma unroll
    for (int a = 0; a < 4; a++)
#pragma unroll
        for (int c = 0; c < 4; c++) acc[a][c] = (f32x4){0.f, 0.f, 0.f, 0.f};

    for (int t = 0; t < 9; t++) {
        int cur = t & 1;
        uint4 pf0, pf1;
        if (t < 8) {   // prefetch next tap (16 u16/thread)
            const uint4* src = (const uint4*)(wH + ((t + 1) << 12) + tid * 16);
            pf0 = src[0]; pf1 = src[1];
        }
        int ky = t / 3, kx = t - ky * 3;
        f16x8 wf[2][4];
#pragma unroll
        for (int kb = 0; kb < 2; kb++)
#pragma unroll
            for (int mt = 0; mt < 4; mt++)
                wf[kb][mt] = *(const f16x8*)(&s_w[cur][((((kb << 2) + mt) << 6) + lane) << 3]);
#pragma unroll
        for (int nt = 0; nt < 4; nt++) {
            int row = r0 + nt + ky;
            int p = row * 18 + kx + m;
            int key = p & 7;
            const u16* pin = &s_in[p << 6];
            f16x8 bfr0 = *(const f16x8*)(pin + ((q ^ key) << 3));
            f16x8 bfr1 = *(const f16x8*)(pin + (((4 + q) ^ key) << 3));
#pragma unroll
            for (int mt = 0; mt < 4; mt++)
                acc[mt][nt] = __builtin_amdgcn_mfma_f32_16x16x32_f16(wf[0][mt], bfr0, acc[mt][nt], 0, 0, 0);
#pragma unroll
            for (int mt = 0; mt < 4; mt++)
                acc[mt][nt] = __builtin_amdgcn_mfma_f32_16x16x32_f16(wf[1][mt], bfr1, acc[mt][nt], 0, 0, 0);
        }
        if (t < 8) {
            u16* dst = &s_w[cur ^ 1][tid * 16];
            *(uint4*)(dst) = pf0;
            *(uint4*)(dst + 8) = pf1;
        }
        __syncthreads();
    }

    // epilogue: bias, NHWC f16 store, per-oc stats
    float ss[4][4], sq[4][4];
#pragma unroll
    for (int mt = 0; mt < 4; mt++)
#pragma unroll
        for (int r = 0; r < 4; r++) { ss[mt][r] = 0.f; sq[mt][r] = 0.f; }

#pragma unroll
    for (int mt = 0; mt < 4; mt++) {
        int ocb = (mt << 4) + (q << 2);
        float b0v = s_bias[ocb], b1v = s_bias[ocb + 1], b2v = s_bias[ocb + 2], b3v = s_bias[ocb + 3];
#pragma unroll
        for (int nt = 0; nt < 4; nt++) {
            f32x4 v = acc[mt][nt];
            float v0 = v.x + b0v, v1 = v.y + b1v, v2 = v.z + b2v, v3 = v.w + b3v;
            uint2 o;
            o.x = (unsigned)f2h(v0) | ((unsigned)f2h(v1) << 16);
            o.y = (unsigned)f2h(v2) | ((unsigned)f2h(v3) << 16);
            int y = y0 + r0 + nt, x = x0 + m;
            *(uint2*)(yout + ((((size_t)(b << 16)) + (y << 8) + x) << 6) + ocb) = o;
            ss[mt][0] += v0; ss[mt][1] += v1; ss[mt][2] += v2; ss[mt][3] += v3;
            sq[mt][0] += v0 * v0; sq[mt][1] += v1 * v1; sq[mt][2] += v2 * v2; sq[mt][3] += v3 * v3;
        }
    }
#pragma unroll
    for (int mt = 0; mt < 4; mt++)
#pragma unroll
        for (int r = 0; r < 4; r++) {
#pragma unroll
            for (int msk = 1; msk <= 8; msk <<= 1) {
                ss[mt][r] += __shfl_xor(ss[mt][r], msk);
                sq[mt][r] += __shfl_xor(sq[mt][r], msk);
            }
        }
    if (m == 0) {
#pragma unroll
        for (int mt = 0; mt < 4; mt++)
#pragma unroll
            for (int r = 0; r < 4; r++) {
                int oc = (mt << 4) + (q << 2) + r;
                s_red[wv][oc][0] = ss[mt][r];
                s_red[wv][oc][1] = sq[mt][r];
            }
    }
    __syncthreads();
    if (tid < 128) {
        int oc = tid >> 1, k2 = tid & 1;
        float v = s_red[0][oc][k2] + s_red[1][oc][k2] + s_red[2][oc][k2] + s_red[3][oc][k2];
        partial[(((b << 8) + tile) << 7) + (oc << 1) + k2] = v;
    }
}

// ---- projection 64->1 + residual -> hr (NHWC f16 input)
__global__ __launch_bounds__(256) void proj_kernel(
    const u16* __restrict__ y7, const float* __restrict__ normp,
    const float* __restrict__ wp, const float* __restrict__ bp,
    const float* __restrict__ xin, float* __restrict__ out) {
    __shared__ float wps[576];
    __shared__ float nps[128];
    int tid = threadIdx.x;
    int b = blockIdx.x >> 8;
    for (int i = tid; i < 576; i += 256) wps[i] = wp[i];
    if (tid < 128) nps[tid] = normp[(b << 7) + tid];
    __syncthreads();
    int pxg = blockIdx.x * 256 + tid;
    int px = pxg & 65535;
    int y = px >> 8, x = px & 255;
    float acc = bp[0];
#pragma unroll
    for (int ky = 0; ky < 3; ky++) {
        int iy = clampi(y + ky - 1, 0, 255);
#pragma unroll
        for (int kx = 0; kx < 3; kx++) {
            int ix = clampi(x + kx - 1, 0, 255);
            int t = ky * 3 + kx;
            const u16* gp = y7 + ((((size_t)(b << 16)) + (iy << 8) + ix) << 6);
#pragma unroll
            for (int c8 = 0; c8 < 8; c8++) {
                union { uint4 q; u16 h[8]; } ui;
                ui.q = *(const uint4*)(gp + (c8 << 3));
#pragma unroll
                for (int i = 0; i < 8; i++) {
                    int ch = (c8 << 3) + i;
                    float v = h2f(ui.h[i]);
                    v = lrelu(fmaf(v, nps[ch * 2], nps[ch * 2 + 1]));
                    acc = fmaf(v, wps[ch * 9 + t], acc);
                }
            }
        }
    }
    out[pxg] = acc + xin[pxg];
}

// ---- loss: per (offset,b) sum & sumsq of d = crop - t
__global__ __launch_bounds__(256) void loss_main_kernel(
    const float* __restrict__ hr, const float* __restrict__ target,
    float* __restrict__ lossS) {
    int off = blockIdx.x, b = blockIdx.y;
    int oy = off / 13, ox = off - oy * 13;
    const float* hp = hr + b * HW_ + (oy << 8) + ox;
    const float* tp = target + b * HW_ + (6 << 8) + 6;
    float s = 0.f, s2 = 0.f;
    for (int i = threadIdx.x; i < CROP_ * CROP_; i += 256) {
        int y = i / CROP_;
        int x = i - y * CROP_;
        float d = hp[(y << 8) + x] - tp[(y << 8) + x];
        s += d; s2 += d * d;
    }
    __shared__ float rs[4], rs2[4];
#pragma unroll
    for (int msk = 1; msk < 64; msk <<= 1) { s += __shfl_xor(s, msk); s2 += __shfl_xor(s2, msk); }
    int lane = threadIdx.x & 63, wv = threadIdx.x >> 6;
    if (lane == 0) { rs[wv] = s; rs2[wv] = s2; }
    __syncthreads();
    if (threadIdx.x == 0) {
        lossS[(off * 8 + b) * 2] = rs[0] + rs[1] + rs[2] + rs[3];
        lossS[(off * 8 + b) * 2 + 1] = rs2[0] + rs2[1] + rs2[2] + rs2[3];
    }
}

__global__ void loss_final_kernel(const float* __restrict__ lossS, float* __restrict__ out) {
    int b = threadIdx.x;
    float mn = 0.f;
    if (b < 8) {
        mn = 1e30f;
        for (int off = 0; off < 169; off++) {
            float s = lossS[(off * 8 + b) * 2];
            float s2 = lossS[(off * 8 + b) * 2 + 1];
            float m = s * (1.0f / NPIX_);
            float L = s2 * (1.0f / NPIX_) - m * m;
            mn = fminf(mn, L);
        }
    }
#pragma unroll
    for (int msk = 1; msk < 8; msk <<= 1) mn += __shfl_xor(mn, msk);
    if (b == 0) out[0] = mn * 0.125f;
}

extern "C" void kernel_launch(void* const* d_in, const int* in_sizes, int n_in,
                              void* d_out, int out_size, void* d_ws, size_t ws_size,
                              hipStream_t stream) {
    const float* xIn    = (const float*)d_in[0];
    const float* target = (const float*)d_in[1];
    const float* w0     = (const float*)d_in[2];
    const float* b0     = (const float*)d_in[3];
    const float* wsAll  = (const float*)d_in[4];
    const float* bsAll  = (const float*)d_in[5];
    const float* wp     = (const float*)d_in[6];
    const float* bp     = (const float*)d_in[7];
    float* out = (float*)d_out;

    float* normp   = (float*)d_ws;                 // 1,024 f
    float* partial = normp + 1024;                 // 262,144 f
    float* lossS   = partial + 262144;             // 2,704 f
    u16*  wH       = (u16*)(lossS + 2704);         // 258,048 u16
    u16*  bufA     = wH + 258048;                  // 33,554,432 u16 (64 MiB)
    u16*  bufB     = bufA + 33554432;              // 33,554,432 u16 (64 MiB)

    wtrans_kernel<<<1008, 256, 0, stream>>>(wsAll, wH);
    conv0_kernel<<<2048, 256, 0, stream>>>(xIn, w0, b0, bufA);
    stats0_kernel<<<dim3(256, 8), 256, 0, stream>>>(bufA, partial);
    statfin_kernel<<<2, 256, 0, stream>>>(partial, normp);
    for (int l = 0; l < 7; l++) {
        const u16* in = (l & 1) ? bufB : bufA;
        u16* o = (l & 1) ? bufA : bufB;
        conv_mid_kernel<<<dim3(256, 8), 256, 0, stream>>>(
            in, normp, wH + l * 36864, bsAll + l * 64, o, partial);
        statfin_kernel<<<2, 256, 0, stream>>>(partial, normp);
    }
    proj_kernel<<<2048, 256, 0, stream>>>(bufB, normp, wp, bp, xIn, out);
    loss_main_kernel<<<dim3(169, 8), 256, 0, stream>>>(out, target, lossS);
    loss_final_kernel<<<1, 64, 0, stream>>>(lossS, out + 524288);
}